// Round 7
// baseline (173.834 us; speedup 1.0000x reference)
//
#include <hip/hip_runtime.h>
#include <cstdint>

// Head attention: x[4,4096,1024] fp32, Wq/Wk/Wv[1024,64] fp32 -> out[4,4096,64] fp32.
// Round 7: r6's DMA loops were overlap-starved (2 blocks/CU). Now 1024 blocks = 4/CU in
// both kernels + BK=64 in qkv (half the barrier drains).
//  K0: wt_prep  - W -> bf16 per-64k-step LDS-image slabs (flat DMA in qkv); Wq pre-scaled
//  K1: qkv_proj - 16-row blocks, per step DMA x(4KB)+W(24KB), 6 MFMA/wave/step,
//                 writes qw plain + K/V pre-tiled per-kv-tile slabs
//  K2: flash    - 16 q-rows/block, 2 waves = 2 kv parities, DMA 2 tiles/round (32KB),
//                 no softmax max (exp2 domain), ones-MFMA row sums, parity LDS combine.

typedef __bf16 bf16;
typedef __bf16 bf16x8 __attribute__((ext_vector_type(8)));
typedef float  f32x4  __attribute__((ext_vector_type(4)));

#define MFMA16(a, b, c) __builtin_amdgcn_mfma_f32_16x16x32_bf16((a), (b), (c), 0, 0, 0)

#if __has_builtin(__builtin_amdgcn_exp2f)
#define EXP2(x) __builtin_amdgcn_exp2f(x)
#else
#define EXP2(x) exp2f(x)
#endif

#define B_SZ 4
#define T_SZ 4096
#define C_SZ 1024
#define H_SZ 64
#define M_SZ (B_SZ * T_SZ)
#define QSCALE (1.4426950408889634f / 32.0f)   // log2(e)/sqrt(1024)

// async 16B global->LDS DMA; LDS dest is wave-uniform base + lane*16.
__device__ __forceinline__ void dma16(const void* g, void* l) {
    __builtin_amdgcn_global_load_lds(
        (const __attribute__((address_space(1))) uint32_t*)(uintptr_t)g,
        (__attribute__((address_space(3))) uint32_t*)(uint32_t)(uintptr_t)l,
        16, 0, 0);
}

// -------------------------------------------------------------------------
// K0: wt2 image, per outer step s (64 k): elem off =
//   s*12288 + sub*6144 + quad*1536 + n*8 + j   where k = s*64+sub*32+quad*8+j,
//   n = 0..191 fused col (which = n/64). Wq pre-scaled by QSCALE. grid 48x256.
// -------------------------------------------------------------------------
__global__ __launch_bounds__(256) void wt_prep(
    const float* __restrict__ Wq, const float* __restrict__ Wk,
    const float* __restrict__ Wv, bf16* __restrict__ wt2)
{
    const int n4 = blockIdx.x, t = threadIdx.x;
    const int nbase = n4 * 4;
    const float* W = (nbase < 64) ? Wq : (nbase < 128 ? Wk : Wv);
    const float sc = (nbase < 64) ? QSCALE : 1.0f;
    const int ncol = nbase & 63;
    #pragma unroll
    for (int i = 0; i < 4; ++i) {
        const int k = i * 256 + t;
        const float4 v = *(const float4*)(W + (size_t)k * H_SZ + ncol);
        const float vals[4] = {v.x, v.y, v.z, v.w};
        const size_t base = (size_t)(k >> 6) * 12288 + (size_t)((k >> 5) & 1) * 6144
                          + (size_t)((k >> 3) & 3) * 1536 + (k & 7);
        #pragma unroll
        for (int m = 0; m < 4; ++m)
            wt2[base + (size_t)(nbase + m) * 8] = (bf16)(vals[m] * sc);
    }
}

// -------------------------------------------------------------------------
// K1: qkv. grid 1024 x 256 (4 waves). Block = 16 rows x 192 fused cols.
// 16 outer steps of BK=64: DMA x slab [sub][quad][row16][8f] (4KB) + W slab
// (24KB). Wave w owns ntiles 3w..3w+2 -> 6 MFMA/step. 4 blocks/CU.
// -------------------------------------------------------------------------
__global__ __launch_bounds__(256) void qkv_proj(
    const float* __restrict__ x, const bf16* __restrict__ wt2,
    bf16* __restrict__ qw, bf16* __restrict__ kw2, bf16* __restrict__ vtw2)
{
    const int m0 = blockIdx.x * 16;
    const int tid = threadIdx.x;
    const int wave = tid >> 6, lane = tid & 63;
    const int quad = lane >> 4, l15 = lane & 15;

    __shared__ __align__(16) float xs[2 * 4 * 16 * 8];   // 4 KB
    __shared__ __align__(16) bf16  ws[2 * 4 * 192 * 8];  // 24 KB

    f32x4 acc[3] = {};

    // x DMA granule tid: sub=tid>>7, q=(tid>>5)&3, row=(tid>>1)&15, half=tid&1
    const char* xg = (const char*)x
        + (size_t)(m0 + ((tid >> 1) & 15)) * 4096
        + (size_t)(tid >> 7) * 128 + (size_t)((tid >> 5) & 3) * 32 + (size_t)(tid & 1) * 16;
    char* xl = (char*)xs + (size_t)tid * 16;
    const char* wg = (const char*)wt2 + (size_t)tid * 16;
    char* wl = (char*)ws + (size_t)tid * 16;

    for (int s = 0; s < 16; ++s) {
        __syncthreads();                               // prior reads done
        dma16(xg + (size_t)s * 256, xl);
        #pragma unroll
        for (int i = 0; i < 6; ++i)
            dma16(wg + (size_t)s * 24576 + (size_t)i * 4096, wl + (size_t)i * 4096);
        __syncthreads();                               // drain -> slabs visible

        #pragma unroll
        for (int ss = 0; ss < 2; ++ss) {
            bf16x8 a;
            {
                const float* ap = xs + ss * 512 + quad * 128 + l15 * 8;
                const f32x4 lo = *(const f32x4*)ap;
                const f32x4 hi = *(const f32x4*)(ap + 4);
                a[0] = (bf16)lo[0]; a[1] = (bf16)lo[1];
                a[2] = (bf16)lo[2]; a[3] = (bf16)lo[3];
                a[4] = (bf16)hi[0]; a[5] = (bf16)hi[1];
                a[6] = (bf16)hi[2]; a[7] = (bf16)hi[3];
            }
            #pragma unroll
            for (int i = 0; i < 3; ++i) {
                const int nt = wave * 3 + i;
                const bf16x8 wf = *(const bf16x8*)(ws + ss * 6144 + quad * 1536
                                                   + (nt * 16 + l15) * 8);
                acc[i] = MFMA16(a, wf, acc[i]);
            }
        }
    }

    // epilogue: row t = m0+quad*4+r, col n = (wave*3+i)*16+l15
    #pragma unroll
    for (int i = 0; i < 3; ++i) {
        const int n = (wave * 3 + i) * 16 + l15;
        const int which = n >> 6, col = n & 63;
        #pragma unroll
        for (int r = 0; r < 4; ++r) {
            const int t = m0 + quad * 4 + r;
            const bf16 v = (bf16)acc[i][r];
            if (which == 0) {
                qw[(size_t)t * H_SZ + col] = v;
            } else if (which == 1) {
                // K slab: jt*4096 + ((col>>5)*4 + ((col>>3)&3))*512 + (t&63)*8 + (col&7)
                kw2[(size_t)(t >> 6) * 4096
                    + (size_t)(((col >> 5) << 2) + ((col >> 3) & 3)) * 512
                    + (size_t)(t & 63) * 8 + (col & 7)] = v;
            } else {
                // V slab: jt*4096 + ((((t>>5)&1)<<2) + ((t>>3)&3))*512 + col*8 + (t&7)
                vtw2[(size_t)(t >> 6) * 4096
                     + (size_t)((((t >> 5) & 1) << 2) + ((t >> 3) & 3)) * 512
                     + (size_t)col * 8 + (t & 7)] = v;
            }
        }
    }
}

// -------------------------------------------------------------------------
// K2: causal flash. grid 1024 x 128 (2 waves). Block = 16 q-rows; wave =
// kv-tile parity. Per round DMA 2 tiles (32KB: K 8K + V 8K each). qt map
// alternates long/short for balance. Parity combine through LDS (aliases
// the P buffers). 4 blocks/CU.
// -------------------------------------------------------------------------
__global__ __launch_bounds__(128) void flash_attn(
    const bf16* __restrict__ qw, const bf16* __restrict__ kw2,
    const bf16* __restrict__ vtw2, float* __restrict__ out)
{
    const int bx = blockIdx.x;
    const int b = bx & 3;
    const int it = bx >> 2;                            // 0..255
    const int qt = (it & 1) ? (255 - (it >> 1)) : (it >> 1);
    const int i0 = qt * 16;
    const int nkv = (qt >> 2) + 1;                     // 64-col kv tiles needed
    const int R = (nkv + 1) >> 1;

    const int tid = threadIdx.x;
    const int par = tid >> 6, lane = tid & 63;
    const int quad = lane >> 4, l15 = lane & 15;

    __shared__ __align__(16) bf16 kvs[16384];          // 32 KB: [slot]{K 8K, V 8K}
    __shared__ __align__(16) char aux[4608];           // pls[2][16*72] bf16  |u| comb
    bf16*  pl   = (bf16*)(aux + par * 2304);
    float* comb = (float*)aux;

    // Q fragments (A-layout): rows i0+l15
    bf16x8 aq0, aq1;
    {
        const bf16* qp = qw + ((size_t)b * T_SZ + i0 + l15) * H_SZ + quad * 8;
        aq0 = *(const bf16x8*)qp;
        aq1 = *(const bf16x8*)(qp + 32);
    }
    const bf16 onev = (bf16)1.0f;
    const bf16x8 vone = {onev, onev, onev, onev, onev, onev, onev, onev};

    const char* kgb = (const char*)kw2 + (size_t)b * 524288;
    const char* vgb = (const char*)vtw2 + (size_t)b * 524288;
    const bf16* kb = kvs + par * 8192;                 // this parity's K slab
    const bf16* vb = kb + 4096;

    f32x4 o[4] = {};
    f32x4 osum = {};

    for (int r = 0; r < R; ++r) {
        const int j0 = 2 * r;
        __syncthreads();                               // prior round's reads done
        {
            const char* ks = kgb + (size_t)j0 * 8192;
            const char* vs = vgb + (size_t)j0 * 8192;
            char* dst = (char*)kvs + (size_t)tid * 16;
            #pragma unroll
            for (int c = 0; c < 4; ++c) {
                dma16(ks + (size_t)c * 2048 + (size_t)tid * 16, dst + c * 2048);
                dma16(vs + (size_t)c * 2048 + (size_t)tid * 16, dst + 8192 + c * 2048);
            }
            if (j0 + 1 < nkv) {
                #pragma unroll
                for (int c = 0; c < 4; ++c) {
                    dma16(ks + 8192 + (size_t)c * 2048 + (size_t)tid * 16, dst + 16384 + c * 2048);
                    dma16(vs + 8192 + (size_t)c * 2048 + (size_t)tid * 16, dst + 24576 + c * 2048);
                }
            }
        }
        __syncthreads();                               // drain -> slabs visible

        const int jt = j0 + par;
        if (jt < nkv) {
            // S = Q K^T : K frag at kb[(kh*4+quad)*512 + (ct*16+l15)*8]
            f32x4 s4[4] = {};
            #pragma unroll
            for (int ct = 0; ct < 4; ++ct) {
                const bf16x8 k0 = *(const bf16x8*)(kb + (0 * 4 + quad) * 512 + (ct * 16 + l15) * 8);
                const bf16x8 k1 = *(const bf16x8*)(kb + (1 * 4 + quad) * 512 + (ct * 16 + l15) * 8);
                s4[ct] = MFMA16(aq0, k0, s4[ct]);
                s4[ct] = MFMA16(aq1, k1, s4[ct]);
            }
            if (jt == nkv - 1) {                       // diagonal: mask col > row
                #pragma unroll
                for (int ct = 0; ct < 4; ++ct) {
                    const int col = jt * 64 + ct * 16 + l15;
                    const int row = i0 + quad * 4;
                    #pragma unroll
                    for (int rr = 0; rr < 4; ++rr)
                        if (col > row + rr) s4[ct][rr] = -3.0e38f;
                }
            }
            // P = exp2(s): C-layout -> per-wave LDS -> A-layout
            #pragma unroll
            for (int ct = 0; ct < 4; ++ct)
                #pragma unroll
                for (int rr = 0; rr < 4; ++rr)
                    pl[(quad * 4 + rr) * 72 + ct * 16 + l15] = (bf16)EXP2(s4[ct][rr]);
            bf16x8 pa0 = *(const bf16x8*)&pl[l15 * 72 + quad * 8];
            bf16x8 pa1 = *(const bf16x8*)&pl[l15 * 72 + 32 + quad * 8];

            // O += P V : V frag at vb[(th*4+quad)*512 + (ht*16+l15)*8]
            #pragma unroll
            for (int ht = 0; ht < 4; ++ht) {
                const bf16x8 v0 = *(const bf16x8*)(vb + (0 * 4 + quad) * 512 + (ht * 16 + l15) * 8);
                const bf16x8 v1 = *(const bf16x8*)(vb + (1 * 4 + quad) * 512 + (ht * 16 + l15) * 8);
                o[ht] = MFMA16(pa0, v0, o[ht]);
                o[ht] = MFMA16(pa1, v1, o[ht]);
            }
            osum = MFMA16(pa0, vone, osum);
            osum = MFMA16(pa1, vone, osum);
        }
    }

    __syncthreads();                                   // last pl reads done (comb aliases pl)
    if (par == 1) {
        #pragma unroll
        for (int ht = 0; ht < 4; ++ht)
            #pragma unroll
            for (int rr = 0; rr < 4; ++rr)
                comb[(quad * 4 + rr) * 64 + ht * 16 + l15] = o[ht][rr];
        if (l15 == 0) {
            #pragma unroll
            for (int rr = 0; rr < 4; ++rr)
                comb[1024 + quad * 4 + rr] = osum[rr];
        }
    }
    __syncthreads();
    if (par == 0) {
        float inv[4];
        #pragma unroll
        for (int rr = 0; rr < 4; ++rr)
            inv[rr] = 1.0f / (osum[rr] + comb[1024 + quad * 4 + rr]);
        #pragma unroll
        for (int ht = 0; ht < 4; ++ht)
            #pragma unroll
            for (int rr = 0; rr < 4; ++rr) {
                const float v = (o[ht][rr] + comb[(quad * 4 + rr) * 64 + ht * 16 + l15]) * inv[rr];
                out[((size_t)b * T_SZ + i0 + quad * 4 + rr) * H_SZ + ht * 16 + l15] = v;
            }
    }
}

extern "C" void kernel_launch(void* const* d_in, const int* in_sizes, int n_in,
                              void* d_out, int out_size, void* d_ws, size_t ws_size,
                              hipStream_t stream) {
    const float* x  = (const float*)d_in[0];
    const float* Wq = (const float*)d_in[1];
    const float* Wk = (const float*)d_in[2];
    const float* Wv = (const float*)d_in[3];

    bf16* qw   = (bf16*)d_ws;                          // 2 MB, plain [t][h]
    bf16* kw2  = qw + (size_t)M_SZ * H_SZ;             // 2 MB, per-kv-tile slabs
    bf16* vtw2 = kw2 + (size_t)M_SZ * H_SZ;            // 2 MB, per-kv-tile slabs
    bf16* wt2  = vtw2 + (size_t)M_SZ * H_SZ;           // 384 KB, per-step slabs
    float* out = (float*)d_out;

    wt_prep<<<48, 256, 0, stream>>>(Wq, Wk, Wv, wt2);
    qkv_proj<<<M_SZ / 16, 256, 0, stream>>>(x, wt2, qw, kw2, vtw2);
    flash_attn<<<1024, 128, 0, stream>>>(qw, kw2, vtw2, out);
}

// Round 8
// 162.886 us; speedup vs baseline: 1.0672x; 1.0672x over previous
//
#include <hip/hip_runtime.h>
#include <cstdint>

// Head attention: x[4,4096,1024] fp32, Wq/Wk/Wv[1024,64] fp32 -> out[4,4096,64] fp32.
// Round 8: flash rebuilt around KV-traffic minimization: 64 q-rows/block (4 waves share
// each 16KB KV slab), 4-way strided KV split -> 1024 blocks (4/CU), additive (no-max)
// partials to ws + combine kernel. KV L2 traffic 557MB (r7) -> 133MB.
//  K0: wt_prep  - W -> bf16 per-64k-step LDS-image slabs; Wq pre-scaled (unchanged r7)
//  K1: qkv_proj - 16-row blocks, BK=64 DMA staging (unchanged r7)
//  K2: flash    - item (b, qt64, h4): waves = 4 row-groups, sweep jt = h, h+4, ...
//  K3: combine  - out = sum_h O_h / sum_h l_h

typedef __bf16 bf16;
typedef __bf16 bf16x8 __attribute__((ext_vector_type(8)));
typedef float  f32x4  __attribute__((ext_vector_type(4)));

#define MFMA16(a, b, c) __builtin_amdgcn_mfma_f32_16x16x32_bf16((a), (b), (c), 0, 0, 0)

#if __has_builtin(__builtin_amdgcn_exp2f)
#define EXP2(x) __builtin_amdgcn_exp2f(x)
#else
#define EXP2(x) exp2f(x)
#endif

#define B_SZ 4
#define T_SZ 4096
#define C_SZ 1024
#define H_SZ 64
#define M_SZ (B_SZ * T_SZ)
#define QSCALE (1.4426950408889634f / 32.0f)   // log2(e)/sqrt(1024)
#define P_STR 4160                             // floats per partial: 64x64 O + 64 l

// async 16B global->LDS DMA; LDS dest is wave-uniform base + lane*16.
__device__ __forceinline__ void dma16(const void* g, void* l) {
    __builtin_amdgcn_global_load_lds(
        (const __attribute__((address_space(1))) uint32_t*)(uintptr_t)g,
        (__attribute__((address_space(3))) uint32_t*)(uint32_t)(uintptr_t)l,
        16, 0, 0);
}

// -------------------------------------------------------------------------
// K0: wt2 image, per 64-k outer step s: elem off =
//   s*12288 + sub*6144 + quad*1536 + n*8 + j  (k = s*64+sub*32+quad*8+j, n = 0..191).
// -------------------------------------------------------------------------
__global__ __launch_bounds__(256) void wt_prep(
    const float* __restrict__ Wq, const float* __restrict__ Wk,
    const float* __restrict__ Wv, bf16* __restrict__ wt2)
{
    const int n4 = blockIdx.x, t = threadIdx.x;
    const int nbase = n4 * 4;
    const float* W = (nbase < 64) ? Wq : (nbase < 128 ? Wk : Wv);
    const float sc = (nbase < 64) ? QSCALE : 1.0f;
    const int ncol = nbase & 63;
    #pragma unroll
    for (int i = 0; i < 4; ++i) {
        const int k = i * 256 + t;
        const float4 v = *(const float4*)(W + (size_t)k * H_SZ + ncol);
        const float vals[4] = {v.x, v.y, v.z, v.w};
        const size_t base = (size_t)(k >> 6) * 12288 + (size_t)((k >> 5) & 1) * 6144
                          + (size_t)((k >> 3) & 3) * 1536 + (k & 7);
        #pragma unroll
        for (int m = 0; m < 4; ++m)
            wt2[base + (size_t)(nbase + m) * 8] = (bf16)(vals[m] * sc);
    }
}

// -------------------------------------------------------------------------
// K1: qkv (unchanged r7). grid 1024 x 256. 16 rows x 192 cols, 16 steps BK=64.
// -------------------------------------------------------------------------
__global__ __launch_bounds__(256) void qkv_proj(
    const float* __restrict__ x, const bf16* __restrict__ wt2,
    bf16* __restrict__ qw, bf16* __restrict__ kw2, bf16* __restrict__ vtw2)
{
    const int m0 = blockIdx.x * 16;
    const int tid = threadIdx.x;
    const int wave = tid >> 6, lane = tid & 63;
    const int quad = lane >> 4, l15 = lane & 15;

    __shared__ __align__(16) float xs[2 * 4 * 16 * 8];   // 4 KB
    __shared__ __align__(16) bf16  ws[2 * 4 * 192 * 8];  // 24 KB

    f32x4 acc[3] = {};

    const char* xg = (const char*)x
        + (size_t)(m0 + ((tid >> 1) & 15)) * 4096
        + (size_t)(tid >> 7) * 128 + (size_t)((tid >> 5) & 3) * 32 + (size_t)(tid & 1) * 16;
    char* xl = (char*)xs + (size_t)tid * 16;
    const char* wg = (const char*)wt2 + (size_t)tid * 16;
    char* wl = (char*)ws + (size_t)tid * 16;

    for (int s = 0; s < 16; ++s) {
        __syncthreads();
        dma16(xg + (size_t)s * 256, xl);
        #pragma unroll
        for (int i = 0; i < 6; ++i)
            dma16(wg + (size_t)s * 24576 + (size_t)i * 4096, wl + (size_t)i * 4096);
        __syncthreads();

        #pragma unroll
        for (int ss = 0; ss < 2; ++ss) {
            bf16x8 a;
            {
                const float* ap = xs + ss * 512 + quad * 128 + l15 * 8;
                const f32x4 lo = *(const f32x4*)ap;
                const f32x4 hi = *(const f32x4*)(ap + 4);
                a[0] = (bf16)lo[0]; a[1] = (bf16)lo[1];
                a[2] = (bf16)lo[2]; a[3] = (bf16)lo[3];
                a[4] = (bf16)hi[0]; a[5] = (bf16)hi[1];
                a[6] = (bf16)hi[2]; a[7] = (bf16)hi[3];
            }
            #pragma unroll
            for (int i = 0; i < 3; ++i) {
                const int nt = wave * 3 + i;
                const bf16x8 wf = *(const bf16x8*)(ws + ss * 6144 + quad * 1536
                                                   + (nt * 16 + l15) * 8);
                acc[i] = MFMA16(a, wf, acc[i]);
            }
        }
    }

    #pragma unroll
    for (int i = 0; i < 3; ++i) {
        const int n = (wave * 3 + i) * 16 + l15;
        const int which = n >> 6, col = n & 63;
        #pragma unroll
        for (int r = 0; r < 4; ++r) {
            const int t = m0 + quad * 4 + r;
            const bf16 v = (bf16)acc[i][r];
            if (which == 0) {
                qw[(size_t)t * H_SZ + col] = v;
            } else if (which == 1) {
                kw2[(size_t)(t >> 6) * 4096
                    + (size_t)(((col >> 5) << 2) + ((col >> 3) & 3)) * 512
                    + (size_t)(t & 63) * 8 + (col & 7)] = v;
            } else {
                vtw2[(size_t)(t >> 6) * 4096
                     + (size_t)((((t >> 5) & 1) << 2) + ((t >> 3) & 3)) * 512
                     + (size_t)col * 8 + (t & 7)] = v;
            }
        }
    }
}

// -------------------------------------------------------------------------
// K2: causal flash. grid 1024 x 256 (4 waves). Item (b, qt64, h): 64 q-rows,
// wave = 16-row group; all 4 waves share each 16KB K/V slab; sweep
// jt = h, h+4, ... <= qt. No softmax max (exp2 domain) -> additive partials
// (O 64x64 + l 64) to pbuf. Long/short launch interleave for balance.
// -------------------------------------------------------------------------
__global__ __launch_bounds__(256) void flash_attn(
    const bf16* __restrict__ qw, const bf16* __restrict__ kw2,
    const bf16* __restrict__ vtw2, float* __restrict__ pbuf)
{
    const int bx = blockIdx.x;
    const int item = (bx & 1) ? (1023 - (bx >> 1)) : (bx >> 1);
    const int qt = 63 - (item >> 4);
    const int b  = (item >> 2) & 3;
    const int h  = item & 3;
    const int i0 = qt * 64;
    const int nkv = qt + 1;

    const int tid = threadIdx.x;
    const int mg = tid >> 6, lane = tid & 63;
    const int quad = lane >> 4, l15 = lane & 15;

    __shared__ __align__(16) bf16 kvs[8192];        // 16 KB: K 8K | V 8K
    __shared__ __align__(16) bf16 pls[4][16 * 72];  // 9.2 KB

    bf16x8 aq0, aq1;
    {
        const bf16* qp = qw + ((size_t)b * T_SZ + i0 + mg * 16 + l15) * H_SZ + quad * 8;
        aq0 = *(const bf16x8*)qp;
        aq1 = *(const bf16x8*)(qp + 32);
    }
    const bf16 onev = (bf16)1.0f;
    const bf16x8 vone = {onev, onev, onev, onev, onev, onev, onev, onev};

    const char* kgb = (const char*)kw2 + (size_t)b * 524288;
    const char* vgb = (const char*)vtw2 + (size_t)b * 524288;
    const bf16* kb = kvs;
    const bf16* vb = kvs + 4096;
    bf16* pl = pls[mg];

    f32x4 o[4] = {};
    f32x4 osum = {};

    for (int jt = h; jt < nkv; jt += 4) {
        __syncthreads();                            // prior round's slab reads done
        {
            const char* ks = kgb + (size_t)jt * 8192;
            const char* vs = vgb + (size_t)jt * 8192;
            char* dst = (char*)kvs + (size_t)tid * 16;
            dma16(ks + (size_t)tid * 16, dst);
            dma16(ks + 4096 + (size_t)tid * 16, dst + 4096);
            dma16(vs + (size_t)tid * 16, dst + 8192);
            dma16(vs + 4096 + (size_t)tid * 16, dst + 12288);
        }
        __syncthreads();                            // drain -> slab visible

        // S = Q K^T  (K frag: kb[(kh*4+quad)*512 + (ct*16+l15)*8])
        f32x4 s4[4] = {};
        #pragma unroll
        for (int ct = 0; ct < 4; ++ct) {
            const bf16x8 k0 = *(const bf16x8*)(kb + (0 * 4 + quad) * 512 + (ct * 16 + l15) * 8);
            const bf16x8 k1 = *(const bf16x8*)(kb + (1 * 4 + quad) * 512 + (ct * 16 + l15) * 8);
            s4[ct] = MFMA16(aq0, k0, s4[ct]);
            s4[ct] = MFMA16(aq1, k1, s4[ct]);
        }
        if (jt == qt) {                             // true diagonal tile: mask col > row
            #pragma unroll
            for (int ct = 0; ct < 4; ++ct) {
                const int col = ct * 16 + l15;               // tile-local == global-i0
                const int row = mg * 16 + quad * 4;
                #pragma unroll
                for (int rr = 0; rr < 4; ++rr)
                    if (col > row + rr) s4[ct][rr] = -3.0e38f;
            }
        }
        // P = exp2(s): C-layout -> per-wave LDS -> A-layout
        #pragma unroll
        for (int ct = 0; ct < 4; ++ct)
            #pragma unroll
            for (int rr = 0; rr < 4; ++rr)
                pl[(quad * 4 + rr) * 72 + ct * 16 + l15] = (bf16)EXP2(s4[ct][rr]);
        const bf16x8 pa0 = *(const bf16x8*)&pl[l15 * 72 + quad * 8];
        const bf16x8 pa1 = *(const bf16x8*)&pl[l15 * 72 + 32 + quad * 8];

        // O += P V  (V frag: vb[(th*4+quad)*512 + (ht*16+l15)*8])
        #pragma unroll
        for (int ht = 0; ht < 4; ++ht) {
            const bf16x8 v0 = *(const bf16x8*)(vb + (0 * 4 + quad) * 512 + (ht * 16 + l15) * 8);
            const bf16x8 v1 = *(const bf16x8*)(vb + (1 * 4 + quad) * 512 + (ht * 16 + l15) * 8);
            o[ht] = MFMA16(pa0, v0, o[ht]);
            o[ht] = MFMA16(pa1, v1, o[ht]);
        }
        osum = MFMA16(pa0, vone, osum);
        osum = MFMA16(pa1, vone, osum);
    }

    // write additive partial (zero for empty items)
    float* pb = pbuf + (size_t)(((b * 64 + qt) * 4) + h) * P_STR;
    #pragma unroll
    for (int ht = 0; ht < 4; ++ht)
        #pragma unroll
        for (int rr = 0; rr < 4; ++rr)
            pb[(mg * 16 + quad * 4 + rr) * 64 + ht * 16 + l15] = o[ht][rr];
    if (l15 == 0) {
        #pragma unroll
        for (int rr = 0; rr < 4; ++rr)
            pb[4096 + mg * 16 + quad * 4 + rr] = osum[rr];
    }
}

// -------------------------------------------------------------------------
// K3: combine. grid 256 (= b*64+qt) x 256. out = sum_h O_h / sum_h l_h.
// Thread -> row tid>>2, cols (tid&3)*16..+16.
// -------------------------------------------------------------------------
__global__ __launch_bounds__(256) void combine(
    const float* __restrict__ pbuf, float* __restrict__ out)
{
    const int bq = blockIdx.x, tid = threadIdx.x;
    const int row = tid >> 2, c0 = (tid & 3) * 16;
    const float* p = pbuf + (size_t)bq * 4 * P_STR;

    f32x4 a0 = {}, a1 = {}, a2 = {}, a3 = {};
    float l = 0.f;
    #pragma unroll
    for (int h = 0; h < 4; ++h) {
        const float* ph = p + (size_t)h * P_STR + row * 64 + c0;
        a0 += *(const f32x4*)(ph);
        a1 += *(const f32x4*)(ph + 4);
        a2 += *(const f32x4*)(ph + 8);
        a3 += *(const f32x4*)(ph + 12);
        l  += p[(size_t)h * P_STR + 4096 + row];
    }
    const float inv = 1.0f / l;
    float* op = out + ((size_t)bq * 64 + row) * 64 + c0;
    *(f32x4*)(op)      = a0 * inv;
    *(f32x4*)(op + 4)  = a1 * inv;
    *(f32x4*)(op + 8)  = a2 * inv;
    *(f32x4*)(op + 12) = a3 * inv;
}

extern "C" void kernel_launch(void* const* d_in, const int* in_sizes, int n_in,
                              void* d_out, int out_size, void* d_ws, size_t ws_size,
                              hipStream_t stream) {
    const float* x  = (const float*)d_in[0];
    const float* Wq = (const float*)d_in[1];
    const float* Wk = (const float*)d_in[2];
    const float* Wv = (const float*)d_in[3];

    bf16* qw   = (bf16*)d_ws;                          // 2 MB, plain [t][h]
    bf16* kw2  = qw + (size_t)M_SZ * H_SZ;             // 2 MB, per-kv-tile slabs
    bf16* vtw2 = kw2 + (size_t)M_SZ * H_SZ;            // 2 MB, per-kv-tile slabs
    bf16* wt2  = vtw2 + (size_t)M_SZ * H_SZ;           // 384 KB, per-step slabs
    float* pbuf = (float*)(wt2 + 3 * 64 * 1024);       // 17 MB partials
    float* out = (float*)d_out;

    wt_prep<<<48, 256, 0, stream>>>(Wq, Wk, Wv, wt2);
    qkv_proj<<<M_SZ / 16, 256, 0, stream>>>(x, wt2, qw, kw2, vtw2);
    flash_attn<<<1024, 256, 0, stream>>>(qw, kw2, vtw2, pbuf);
    combine<<<256, 256, 0, stream>>>(pbuf, out);
}

// Round 9
// 151.103 us; speedup vs baseline: 1.1504x; 1.0780x over previous
//
#include <hip/hip_runtime.h>
#include <cstdint>

// Head attention: x[4,4096,1024] fp32, Wq/Wk/Wv[1024,64] fp32 -> out[4,4096,64] fp32.
// Round 9: qkv rebuilt: 32-row blocks (W re-read traffic halved) + per-block slab-phase
// stagger (kills L2 same-line lockstep contention on wt2). flash/wt_prep/combine frozen.
//  K0: wt_prep  - W -> bf16 per-64k-step LDS-image slabs; Wq pre-scaled
//  K1: qkv_proj - 32-row blocks, BK=64, staggered slab phase, DMA x(8KB)+W(24KB)/step
//  K2: flash    - item (b, qt64, h4): 64 q-rows, 4 waves share 16KB KV slab (r8)
//  K3: combine  - out = sum_h O_h / sum_h l_h (r8)

typedef __bf16 bf16;
typedef __bf16 bf16x8 __attribute__((ext_vector_type(8)));
typedef float  f32x4  __attribute__((ext_vector_type(4)));

#define MFMA16(a, b, c) __builtin_amdgcn_mfma_f32_16x16x32_bf16((a), (b), (c), 0, 0, 0)

#if __has_builtin(__builtin_amdgcn_exp2f)
#define EXP2(x) __builtin_amdgcn_exp2f(x)
#else
#define EXP2(x) exp2f(x)
#endif

#define B_SZ 4
#define T_SZ 4096
#define C_SZ 1024
#define H_SZ 64
#define M_SZ (B_SZ * T_SZ)
#define QSCALE (1.4426950408889634f / 32.0f)   // log2(e)/sqrt(1024)
#define P_STR 4160                             // floats per partial: 64x64 O + 64 l

// async 16B global->LDS DMA; LDS dest is wave-uniform base + lane*16.
__device__ __forceinline__ void dma16(const void* g, void* l) {
    __builtin_amdgcn_global_load_lds(
        (const __attribute__((address_space(1))) uint32_t*)(uintptr_t)g,
        (__attribute__((address_space(3))) uint32_t*)(uint32_t)(uintptr_t)l,
        16, 0, 0);
}

// -------------------------------------------------------------------------
// K0: wt2 image, per 64-k outer step s: elem off =
//   s*12288 + sub*6144 + quad*1536 + n*8 + j  (k = s*64+sub*32+quad*8+j, n = 0..191).
// -------------------------------------------------------------------------
__global__ __launch_bounds__(256) void wt_prep(
    const float* __restrict__ Wq, const float* __restrict__ Wk,
    const float* __restrict__ Wv, bf16* __restrict__ wt2)
{
    const int n4 = blockIdx.x, t = threadIdx.x;
    const int nbase = n4 * 4;
    const float* W = (nbase < 64) ? Wq : (nbase < 128 ? Wk : Wv);
    const float sc = (nbase < 64) ? QSCALE : 1.0f;
    const int ncol = nbase & 63;
    #pragma unroll
    for (int i = 0; i < 4; ++i) {
        const int k = i * 256 + t;
        const float4 v = *(const float4*)(W + (size_t)k * H_SZ + ncol);
        const float vals[4] = {v.x, v.y, v.z, v.w};
        const size_t base = (size_t)(k >> 6) * 12288 + (size_t)((k >> 5) & 1) * 6144
                          + (size_t)((k >> 3) & 3) * 1536 + (k & 7);
        #pragma unroll
        for (int m = 0; m < 4; ++m)
            wt2[base + (size_t)(nbase + m) * 8] = (bf16)(vals[m] * sc);
    }
}

// -------------------------------------------------------------------------
// K1: qkv. grid 512 x 256 (4 waves). Block = 32 rows x 192 fused cols.
// 16 steps of BK=64, slab phase staggered by block. Per step: DMA x slab
// [sub][quad][row32][8f] (8KB) + W slab (24KB); 12 MFMA/wave/step.
// -------------------------------------------------------------------------
__global__ __launch_bounds__(256) void qkv_proj(
    const float* __restrict__ x, const bf16* __restrict__ wt2,
    bf16* __restrict__ qw, bf16* __restrict__ kw2, bf16* __restrict__ vtw2)
{
    const int m0 = blockIdx.x * 32;
    const int tid = threadIdx.x;
    const int wave = tid >> 6, lane = tid & 63;
    const int quad = lane >> 4, l15 = lane & 15;
    const int phase = blockIdx.x & 15;             // slab-phase stagger

    __shared__ __align__(16) float xs[2 * 4 * 32 * 8];   // 8 KB
    __shared__ __align__(16) bf16  ws[2 * 4 * 192 * 8];  // 24 KB

    f32x4 acc[2][3] = {};                          // [mg][ntile]

    // x DMA granule (per thread, i in {0,1}): sub=i, quad=(tid>>6)&3,
    // row=(tid>>1)&31, half=tid&1. k-offset within step: sub*128B+quad*32B+half*16B.
    const char* xg = (const char*)x
        + (size_t)(m0 + ((tid >> 1) & 31)) * 4096
        + (size_t)((tid >> 6) & 3) * 32 + (size_t)(tid & 1) * 16;
    char* xl = (char*)xs + (size_t)tid * 16;
    const char* wg = (const char*)wt2 + (size_t)tid * 16;
    char* wl = (char*)ws + (size_t)tid * 16;

    for (int s = 0; s < 16; ++s) {
        const size_t se = (size_t)((s + phase) & 15);
        __syncthreads();                           // prior step's reads done
        dma16(xg + se * 256, xl);
        dma16(xg + se * 256 + 128, xl + 4096);
        #pragma unroll
        for (int i = 0; i < 6; ++i)
            dma16(wg + se * 24576 + (size_t)i * 4096, wl + (size_t)i * 4096);
        __syncthreads();                           // drain -> slabs visible

        #pragma unroll
        for (int ss = 0; ss < 2; ++ss) {
            bf16x8 a[2];
            #pragma unroll
            for (int mg = 0; mg < 2; ++mg) {
                const float* ap = xs + ss * 1024 + quad * 256 + (mg * 16 + l15) * 8;
                const f32x4 lo = *(const f32x4*)ap;
                const f32x4 hi = *(const f32x4*)(ap + 4);
                a[mg][0] = (bf16)lo[0]; a[mg][1] = (bf16)lo[1];
                a[mg][2] = (bf16)lo[2]; a[mg][3] = (bf16)lo[3];
                a[mg][4] = (bf16)hi[0]; a[mg][5] = (bf16)hi[1];
                a[mg][6] = (bf16)hi[2]; a[mg][7] = (bf16)hi[3];
            }
            #pragma unroll
            for (int i = 0; i < 3; ++i) {
                const int nt = wave * 3 + i;
                const bf16x8 wf = *(const bf16x8*)(ws + ss * 6144 + quad * 1536
                                                   + (nt * 16 + l15) * 8);
                #pragma unroll
                for (int mg = 0; mg < 2; ++mg)
                    acc[mg][i] = MFMA16(a[mg], wf, acc[mg][i]);
            }
        }
    }

    // epilogue: row t = m0+mg*16+quad*4+r, col n = (wave*3+i)*16+l15
    #pragma unroll
    for (int mg = 0; mg < 2; ++mg)
        #pragma unroll
        for (int i = 0; i < 3; ++i) {
            const int n = (wave * 3 + i) * 16 + l15;
            const int which = n >> 6, col = n & 63;
            #pragma unroll
            for (int r = 0; r < 4; ++r) {
                const int t = m0 + mg * 16 + quad * 4 + r;
                const bf16 v = (bf16)acc[mg][i][r];
                if (which == 0) {
                    qw[(size_t)t * H_SZ + col] = v;
                } else if (which == 1) {
                    // K slab: jt*4096 + ((col>>5)*4 + ((col>>3)&3))*512 + (t&63)*8 + (col&7)
                    kw2[(size_t)(t >> 6) * 4096
                        + (size_t)(((col >> 5) << 2) + ((col >> 3) & 3)) * 512
                        + (size_t)(t & 63) * 8 + (col & 7)] = v;
                } else {
                    // V slab: jt*4096 + ((((t>>5)&1)<<2) + ((t>>3)&3))*512 + col*8 + (t&7)
                    vtw2[(size_t)(t >> 6) * 4096
                         + (size_t)((((t >> 5) & 1) << 2) + ((t >> 3) & 3)) * 512
                         + (size_t)col * 8 + (t & 7)] = v;
                }
            }
        }
}

// -------------------------------------------------------------------------
// K2: causal flash (unchanged r8). grid 1024 x 256. Item (b, qt64, h):
// 64 q-rows, 4 waves share each 16KB K/V slab; sweep jt = h, h+4, ...;
// additive partials (no softmax max) to pbuf.
// -------------------------------------------------------------------------
__global__ __launch_bounds__(256) void flash_attn(
    const bf16* __restrict__ qw, const bf16* __restrict__ kw2,
    const bf16* __restrict__ vtw2, float* __restrict__ pbuf)
{
    const int bx = blockIdx.x;
    const int item = (bx & 1) ? (1023 - (bx >> 1)) : (bx >> 1);
    const int qt = 63 - (item >> 4);
    const int b  = (item >> 2) & 3;
    const int h  = item & 3;
    const int i0 = qt * 64;
    const int nkv = qt + 1;

    const int tid = threadIdx.x;
    const int mg = tid >> 6, lane = tid & 63;
    const int quad = lane >> 4, l15 = lane & 15;

    __shared__ __align__(16) bf16 kvs[8192];        // 16 KB: K 8K | V 8K
    __shared__ __align__(16) bf16 pls[4][16 * 72];  // 9.2 KB

    bf16x8 aq0, aq1;
    {
        const bf16* qp = qw + ((size_t)b * T_SZ + i0 + mg * 16 + l15) * H_SZ + quad * 8;
        aq0 = *(const bf16x8*)qp;
        aq1 = *(const bf16x8*)(qp + 32);
    }
    const bf16 onev = (bf16)1.0f;
    const bf16x8 vone = {onev, onev, onev, onev, onev, onev, onev, onev};

    const char* kgb = (const char*)kw2 + (size_t)b * 524288;
    const char* vgb = (const char*)vtw2 + (size_t)b * 524288;
    const bf16* kb = kvs;
    const bf16* vb = kvs + 4096;
    bf16* pl = pls[mg];

    f32x4 o[4] = {};
    f32x4 osum = {};

    for (int jt = h; jt < nkv; jt += 4) {
        __syncthreads();
        {
            const char* ks = kgb + (size_t)jt * 8192;
            const char* vs = vgb + (size_t)jt * 8192;
            char* dst = (char*)kvs + (size_t)tid * 16;
            dma16(ks + (size_t)tid * 16, dst);
            dma16(ks + 4096 + (size_t)tid * 16, dst + 4096);
            dma16(vs + (size_t)tid * 16, dst + 8192);
            dma16(vs + 4096 + (size_t)tid * 16, dst + 12288);
        }
        __syncthreads();

        f32x4 s4[4] = {};
        #pragma unroll
        for (int ct = 0; ct < 4; ++ct) {
            const bf16x8 k0 = *(const bf16x8*)(kb + (0 * 4 + quad) * 512 + (ct * 16 + l15) * 8);
            const bf16x8 k1 = *(const bf16x8*)(kb + (1 * 4 + quad) * 512 + (ct * 16 + l15) * 8);
            s4[ct] = MFMA16(aq0, k0, s4[ct]);
            s4[ct] = MFMA16(aq1, k1, s4[ct]);
        }
        if (jt == qt) {
            #pragma unroll
            for (int ct = 0; ct < 4; ++ct) {
                const int col = ct * 16 + l15;
                const int row = mg * 16 + quad * 4;
                #pragma unroll
                for (int rr = 0; rr < 4; ++rr)
                    if (col > row + rr) s4[ct][rr] = -3.0e38f;
            }
        }
        #pragma unroll
        for (int ct = 0; ct < 4; ++ct)
            #pragma unroll
            for (int rr = 0; rr < 4; ++rr)
                pl[(quad * 4 + rr) * 72 + ct * 16 + l15] = (bf16)EXP2(s4[ct][rr]);
        const bf16x8 pa0 = *(const bf16x8*)&pl[l15 * 72 + quad * 8];
        const bf16x8 pa1 = *(const bf16x8*)&pl[l15 * 72 + 32 + quad * 8];

        #pragma unroll
        for (int ht = 0; ht < 4; ++ht) {
            const bf16x8 v0 = *(const bf16x8*)(vb + (0 * 4 + quad) * 512 + (ht * 16 + l15) * 8);
            const bf16x8 v1 = *(const bf16x8*)(vb + (1 * 4 + quad) * 512 + (ht * 16 + l15) * 8);
            o[ht] = MFMA16(pa0, v0, o[ht]);
            o[ht] = MFMA16(pa1, v1, o[ht]);
        }
        osum = MFMA16(pa0, vone, osum);
        osum = MFMA16(pa1, vone, osum);
    }

    float* pb = pbuf + (size_t)(((b * 64 + qt) * 4) + h) * P_STR;
    #pragma unroll
    for (int ht = 0; ht < 4; ++ht)
        #pragma unroll
        for (int rr = 0; rr < 4; ++rr)
            pb[(mg * 16 + quad * 4 + rr) * 64 + ht * 16 + l15] = o[ht][rr];
    if (l15 == 0) {
        #pragma unroll
        for (int rr = 0; rr < 4; ++rr)
            pb[4096 + mg * 16 + quad * 4 + rr] = osum[rr];
    }
}

// -------------------------------------------------------------------------
// K3: combine (unchanged r8). grid 256 x 256. out = sum_h O_h / sum_h l_h.
// -------------------------------------------------------------------------
__global__ __launch_bounds__(256) void combine(
    const float* __restrict__ pbuf, float* __restrict__ out)
{
    const int bq = blockIdx.x, tid = threadIdx.x;
    const int row = tid >> 2, c0 = (tid & 3) * 16;
    const float* p = pbuf + (size_t)bq * 4 * P_STR;

    f32x4 a0 = {}, a1 = {}, a2 = {}, a3 = {};
    float l = 0.f;
    #pragma unroll
    for (int h = 0; h < 4; ++h) {
        const float* ph = p + (size_t)h * P_STR + row * 64 + c0;
        a0 += *(const f32x4*)(ph);
        a1 += *(const f32x4*)(ph + 4);
        a2 += *(const f32x4*)(ph + 8);
        a3 += *(const f32x4*)(ph + 12);
        l  += p[(size_t)h * P_STR + 4096 + row];
    }
    const float inv = 1.0f / l;
    float* op = out + ((size_t)bq * 64 + row) * 64 + c0;
    *(f32x4*)(op)      = a0 * inv;
    *(f32x4*)(op + 4)  = a1 * inv;
    *(f32x4*)(op + 8)  = a2 * inv;
    *(f32x4*)(op + 12) = a3 * inv;
}

extern "C" void kernel_launch(void* const* d_in, const int* in_sizes, int n_in,
                              void* d_out, int out_size, void* d_ws, size_t ws_size,
                              hipStream_t stream) {
    const float* x  = (const float*)d_in[0];
    const float* Wq = (const float*)d_in[1];
    const float* Wk = (const float*)d_in[2];
    const float* Wv = (const float*)d_in[3];

    bf16* qw   = (bf16*)d_ws;                          // 2 MB, plain [t][h]
    bf16* kw2  = qw + (size_t)M_SZ * H_SZ;             // 2 MB, per-kv-tile slabs
    bf16* vtw2 = kw2 + (size_t)M_SZ * H_SZ;            // 2 MB, per-kv-tile slabs
    bf16* wt2  = vtw2 + (size_t)M_SZ * H_SZ;           // 384 KB, per-step slabs
    float* pbuf = (float*)(wt2 + 3 * 64 * 1024);       // 17 MB partials
    float* out = (float*)d_out;

    wt_prep<<<48, 256, 0, stream>>>(Wq, Wk, Wv, wt2);
    qkv_proj<<<M_SZ / 32, 256, 0, stream>>>(x, wt2, qw, kw2, vtw2);
    flash_attn<<<1024, 256, 0, stream>>>(qw, kw2, vtw2, pbuf);
    combine<<<256, 256, 0, stream>>>(pbuf, out);
}